// Round 8
// baseline (782.210 us; speedup 1.0000x reference)
//
#include <hip/hip_runtime.h>

// GRU_43387759624777 — Round 8: K-term-split wave specialization, 8 waves/CU.
//
// R7 post-mortem: 1467 cyc/step = ~460 VALU + ~310 MFMA + ~640 stall; the
// stall is phase-locked LDS bursts + latency at 1 wave/SIMD. ROWS=16 is forced
// (R4/R6), so co-residency must come from splitting a wave's work: wave pair
// (wA=ub, wB=ub+4) splits the 6 MFMA terms by K-half. wA: kt0 terms (9 MFMA,
// 2 b128 frag reads); wB: kt1 terms, writes 3 f32x4 partials to pbuf. After
// barrier2, wA merges partials + gate math + hfrag write (identical arithmetic
// to R7's accA+accB). wB also owns all x staging. Barriers are non-divergent.
//
// Verified invariants (R3/R5/R7, absmax~0): A/B-frag [dim0=lane&15][k=(lane>>4)*8+j];
// C/D col=lane&15, row=(lane>>4)*4+reg; terms Whi*hhi + Whi*hlo + Wlo*hhi;
// hfrag word = hi | (lo<<16), stride 12 words (2-way bank alias = free).

#define HID 64
#define SEQ 1024
#define BATCH 4096
#define ROWS 16
#define THREADS 512
#define NTB (SEQ / 64)   // 16 t-blocks

typedef __attribute__((ext_vector_type(8))) short short8;
typedef __attribute__((ext_vector_type(4))) float f32x4;
typedef __attribute__((ext_vector_type(4))) unsigned uint4v;

#define SEL_HI 0x05040100u   // hi plane (low halves of packed words)
#define SEL_LO 0x07060302u   // lo plane (high halves)
#define SEL_PACK 0x07060302u // resid[31:16]<<16 | h[31:16]

union FragU { uint4v u; short8 s; };

__device__ __forceinline__ short f2bf(float f) {   // RNE (weights only, once)
  unsigned u = __float_as_uint(f);
  u += 0x7fffu + ((u >> 16) & 1u);
  return (short)(u >> 16);
}
__device__ __forceinline__ float bf2f(short s) {
  return __uint_as_float(((unsigned)(unsigned short)s) << 16);
}
__device__ __forceinline__ float rcp_fast(float x) { return __builtin_amdgcn_rcpf(x); }

__global__ __launch_bounds__(THREADS, 1) void gru_mfma(
    const float* __restrict__ x,     // [B, T]
    const float* __restrict__ w_ih,  // [192, 1]
    const float* __restrict__ w_hh,  // [192, 64]
    const float* __restrict__ b_ih,  // [192]
    const float* __restrict__ b_hh,  // [192]
    const float* __restrict__ w1,    // [32, 64]
    const float* __restrict__ b1,    // [32]
    const float* __restrict__ w2,    // [16, 32]
    const float* __restrict__ b2,    // [16]
    const float* __restrict__ w3,    // [1, 16]
    const float* __restrict__ b3,    // [1]
    float* __restrict__ out)         // [B, 1]
{
  const int L  = threadIdx.x;        // 0..511
  const int l  = L & 63;             // lane in wave
  const int wv = L >> 6;             // wave 0..7
  const bool isA = (wv < 4);         // wave role (wave-uniform)
  const int ub  = wv & 3;            // unit block 0..3 (paired wA/wB share ub)
  const int kts = isA ? 0 : 1;       // K-half this wave computes
  const int r0  = blockIdx.x * ROWS;

  // ---------------- LDS (~37 KB -> 1 block/CU, 8 waves) ----------------
  __shared__ __align__(16) unsigned hfrag[2][2][64][12]; // 12 KB dbuf A-frags
  __shared__ __align__(16) float pbuf[4][64][12];        // 12 KB kt1 partials
  __shared__ float xbuf[2][ROWS][68];                    // dbuf x chunks
  __shared__ float ybuf1[ROWS][36];
  __shared__ float ybuf2[ROWS][20];

  // ---------------- W fragments: only this wave's K-half ----------------
  // B-frag: lane holds w_hh[(gate*4+ub)*16 + (l&15)][kts*32 + (l>>4)*8 + j]
  short8 bhi[3], blo[3];
  {
    const int n0 = l & 15, q = l >> 4;
    #pragma unroll
    for (int gate = 0; gate < 3; ++gate) {
      const int c = (gate * 4 + ub) * 16 + n0;
      const float* p = w_hh + c * HID + kts * 32 + q * 8;
      f32x4 p0 = *(const f32x4*)p;
      f32x4 p1 = *(const f32x4*)(p + 4);
      float vals[8] = {p0[0], p0[1], p0[2], p0[3], p1[0], p1[1], p1[2], p1[3]};
      short8 hi8, lo8;
      #pragma unroll
      for (int j = 0; j < 8; ++j) {
        short h8 = f2bf(vals[j]);
        hi8[j] = h8;
        lo8[j] = f2bf(vals[j] - bf2f(h8));
      }
      bhi[gate] = hi8;
      blo[gate] = lo8;
    }
  }

  // ---------------- per-lane elementwise constants (wA role) ----------------
  // Lane owns unit u = 16ub + (l&15), rows 4qq..4qq+3 (qq = l>>4).
  const int u  = 16 * ub + (l & 15);
  const int qq = l >> 4;
  const float wir = w_ih[u], wiz = w_ih[64 + u], win = w_ih[128 + u];
  const float br  = b_ih[u] + b_hh[u];
  const float bz  = b_ih[64 + u] + b_hh[64 + u];
  const float bni = b_ih[128 + u];
  const float bnh = b_hh[128 + u];
  float h[4] = {0.f, 0.f, 0.f, 0.f};

  const int wkt = u >> 5;
  const int wQ  = (u >> 3) & 3;
  const int wj  = u & 7;

  // zero hfrag (h0 = 0)
  for (int i = L; i < 2 * 2 * 64 * 12; i += THREADS) ((unsigned*)hfrag)[i] = 0u;

  const float* xblk = x + (size_t)r0 * SEQ;
  const int sl = L & 255, srow = sl >> 4, stq = sl & 15;  // staging map (wB)

  if (!isA) {  // initial stage tb=0 into xbuf[0]
    f32x4 v = *(const f32x4*)(xblk + (size_t)srow * SEQ + stq * 4);
    *(f32x4*)&xbuf[0][srow][stq * 4] = v;
  }

  // ---------------- scan ----------------
  float xc0, xc1, xc2, xc3;
  for (int tb = 0; tb < NTB; ++tb) {
    const int par = tb & 1;
    const int tbn = (tb < NTB - 1) ? tb + 1 : tb;
    f32x4 xg;
    if (!isA)  // wB prefetches next tb's x (64 steps of latency budget)
      xg = *(const f32x4*)(xblk + (size_t)srow * SEQ + tbn * 64 + stq * 4);

    #pragma unroll 2
    for (int s = 0; s < 64; ++s) {
      const int cur = s & 1, nxt = cur ^ 1;
      __syncthreads();  // barrier0: hfrag[cur] (+ this tb's xbuf) visible

      float xn0, xn1, xn2, xn3;
      if (isA) {
        if (s == 0) {
          xc0 = xbuf[par][4 * qq + 0][0];
          xc1 = xbuf[par][4 * qq + 1][0];
          xc2 = xbuf[par][4 * qq + 2][0];
          xc3 = xbuf[par][4 * qq + 3][0];
        }
        xn0 = xbuf[par][4 * qq + 0][s + 1];  // s=63 reads pad, discarded
        xn1 = xbuf[par][4 * qq + 1][s + 1];
        xn2 = xbuf[par][4 * qq + 2][s + 1];
        xn3 = xbuf[par][4 * qq + 3][s + 1];
      }

      // ---- A-fragments for this wave's K-half: 2 b128 + 8 perms ----
      uint4v ka = *(const uint4v*)&hfrag[cur][kts][l][0];
      uint4v kb = *(const uint4v*)&hfrag[cur][kts][l][4];
      FragU ahi, alo;
      #pragma unroll
      for (int p = 0; p < 2; ++p) {
        ahi.u[p]     = __builtin_amdgcn_perm(ka[2*p+1], ka[2*p], SEL_HI);
        alo.u[p]     = __builtin_amdgcn_perm(ka[2*p+1], ka[2*p], SEL_LO);
        ahi.u[p + 2] = __builtin_amdgcn_perm(kb[2*p+1], kb[2*p], SEL_HI);
        alo.u[p + 2] = __builtin_amdgcn_perm(kb[2*p+1], kb[2*p], SEL_LO);
      }

      // ---- 9 MFMAs: 3 gates x (hi*Whi + lo*Whi + hi*Wlo) for this K-half ----
      f32x4 acc0 = {0.f, 0.f, 0.f, 0.f};
      f32x4 acc1 = {0.f, 0.f, 0.f, 0.f};
      f32x4 acc2 = {0.f, 0.f, 0.f, 0.f};
      acc0 = __builtin_amdgcn_mfma_f32_16x16x32_bf16(ahi.s, bhi[0], acc0, 0, 0, 0);
      acc1 = __builtin_amdgcn_mfma_f32_16x16x32_bf16(ahi.s, bhi[1], acc1, 0, 0, 0);
      acc2 = __builtin_amdgcn_mfma_f32_16x16x32_bf16(ahi.s, bhi[2], acc2, 0, 0, 0);
      acc0 = __builtin_amdgcn_mfma_f32_16x16x32_bf16(alo.s, bhi[0], acc0, 0, 0, 0);
      acc1 = __builtin_amdgcn_mfma_f32_16x16x32_bf16(alo.s, bhi[1], acc1, 0, 0, 0);
      acc2 = __builtin_amdgcn_mfma_f32_16x16x32_bf16(alo.s, bhi[2], acc2, 0, 0, 0);
      acc0 = __builtin_amdgcn_mfma_f32_16x16x32_bf16(ahi.s, blo[0], acc0, 0, 0, 0);
      acc1 = __builtin_amdgcn_mfma_f32_16x16x32_bf16(ahi.s, blo[1], acc1, 0, 0, 0);
      acc2 = __builtin_amdgcn_mfma_f32_16x16x32_bf16(ahi.s, blo[2], acc2, 0, 0, 0);

      if (!isA) {  // wB: publish kt1 partials
        *(f32x4*)&pbuf[ub][l][0] = acc0;
        *(f32x4*)&pbuf[ub][l][4] = acc1;
        *(f32x4*)&pbuf[ub][l][8] = acc2;
      }
      __syncthreads();  // barrier1: partials visible

      if (isA) {
        f32x4 pb0 = *(const f32x4*)&pbuf[ub][l][0];
        f32x4 pb1 = *(const f32x4*)&pbuf[ub][l][4];
        f32x4 pb2 = *(const f32x4*)&pbuf[ub][l][8];
        const float xr[4] = {xc0, xc1, xc2, xc3};
        #pragma unroll
        for (int r = 0; r < 4; ++r) {
          const float xt = xr[r];
          float rpre = (acc0[r] + pb0[r]) + __fmaf_rn(xt, wir, br);
          float rr   = rcp_fast(1.0f + __expf(-rpre));
          float zpre = (acc1[r] + pb1[r]) + __fmaf_rn(xt, wiz, bz);
          float zz   = rcp_fast(1.0f + __expf(-zpre));
          float npre = __fmaf_rn(rr, (acc2[r] + pb2[r]) + bnh,
                                 __fmaf_rn(xt, win, bni));
          float nn   = 1.0f - 2.0f * rcp_fast(__expf(2.0f * npre) + 1.0f);
          h[r] = __fmaf_rn(zz, h[r] - nn, nn);
          float hif   = __uint_as_float(__float_as_uint(h[r]) & 0xFFFF0000u);
          float resid = h[r] - hif;
          unsigned word = __builtin_amdgcn_perm(__float_as_uint(resid),
                                                __float_as_uint(h[r]), SEL_PACK);
          hfrag[nxt][wkt][16 * wQ + 4 * qq + r][wj] = word;
        }
        xc0 = xn0; xc1 = xn1; xc2 = xn2; xc3 = xn3;
      }
    }

    if (!isA)  // stage next tb's x (consumers >=1 barrier away)
      *(f32x4*)&xbuf[par ^ 1][srow][stq * 4] = xg;
  }

  // ---------------- MLP head: 64 -> 32 -> 16 -> 1 ----------------
  __syncthreads();
  if (isA) {
    #pragma unroll
    for (int r = 0; r < 4; ++r) xbuf[0][4 * qq + r][u] = h[r];  // h fp32 -> LDS
  }
  __syncthreads();

  {
    const int o = L & 31, row = L >> 5;          // 16 rows x 32 outs = 512 tasks
    float a = b1[o];
    #pragma unroll
    for (int j4 = 0; j4 < 16; ++j4) {
      f32x4 wv4 = *(const f32x4*)&w1[o * 64 + 4 * j4];
      f32x4 hv  = *(const f32x4*)&xbuf[0][row][4 * j4];
      a += wv4[0] * hv[0] + wv4[1] * hv[1] + wv4[2] * hv[2] + wv4[3] * hv[3];
    }
    ybuf1[row][o] = (a > 0.0f) ? a : 0.01f * a;
  }
  __syncthreads();

  if (L < 256) {
    const int o = L & 15, row = L >> 4;          // 16 rows x 16 outs = 256 tasks
    float a = b2[o];
    #pragma unroll
    for (int j4 = 0; j4 < 8; ++j4) {
      f32x4 wv4 = *(const f32x4*)&w2[o * 32 + 4 * j4];
      f32x4 yv  = *(const f32x4*)&ybuf1[row][4 * j4];
      a += wv4[0] * yv[0] + wv4[1] * yv[1] + wv4[2] * yv[2] + wv4[3] * yv[3];
    }
    ybuf2[row][o] = (a > 0.0f) ? a : 0.01f * a;
  }
  __syncthreads();

  if (L < ROWS) {
    float a = b3[0];
    #pragma unroll
    for (int j = 0; j < 16; ++j) a = __fmaf_rn(w3[j], ybuf2[L][j], a);
    out[r0 + L] = a;
  }
}

extern "C" void kernel_launch(void* const* d_in, const int* in_sizes, int n_in,
                              void* d_out, int out_size, void* d_ws, size_t ws_size,
                              hipStream_t stream) {
  const float* x    = (const float*)d_in[0];
  const float* w_ih = (const float*)d_in[1];
  const float* w_hh = (const float*)d_in[2];
  const float* b_ih = (const float*)d_in[3];
  const float* b_hh = (const float*)d_in[4];
  const float* w1   = (const float*)d_in[5];
  const float* b1   = (const float*)d_in[6];
  const float* w2   = (const float*)d_in[7];
  const float* b2   = (const float*)d_in[8];
  const float* w3   = (const float*)d_in[9];
  const float* b3   = (const float*)d_in[10];
  float* out = (float*)d_out;

  dim3 grid(BATCH / ROWS);  // 256 blocks x 8 waves x 16 rows — work-conserving
  dim3 block(THREADS);
  hipLaunchKernelGGL(gru_mfma, grid, block, 0, stream,
                     x, w_ih, w_hh, b_ih, b_hh, w1, b1, w2, b2, w3, b3, out);
}

// Round 9
// 403.676 us; speedup vs baseline: 1.9377x; 1.9377x over previous
//
#include <hip/hip_runtime.h>

// GRU_43387759624777 — Round 9: R7 one-barrier shape, 1-term fp16 + exp2 prescale.
//
// R8 post-mortem: merge-barrier wave specialization regressed (782 vs 638 µs);
// wB waves idle in phase 2, two barriers on the serial chain. R4/R6/R8 all say:
// keep R7's merge-free one-barrier step. This round shrinks the chain itself:
//  - fp16 single-term MFMA: W,h quantize at 2^-12; error ~1e-4 at output vs
//    1.67e-3 threshold. 18 -> 6 MFMAs/wave-step; A-frag one plane: 2 ds_read_b128,
//    NO unpack perms; h store = cvt_f16 + ds_write_b16.
//  - exp2-domain prescale: r,z weight tiles (+wir/wiz/biases) x(-log2e), n tile
//    x(+2log2e) at init -> v_exp used as exp2 directly, no mul/neg per gate.
//  - f32x4 gate preamble (v_pk_fma), direct x read (no prefetch regs).
//
// Verified invariants (R3..R7): A/B-frag [dim0=lane&15][k=(lane>>4)*8+j];
// C/D col=lane&15, row=(lane>>4)*4+reg (dtype-independent, m121-128);
// hfrag row stride 12 words / 48 B (bank-clean for b128, measured R5-R7).

#define HID 64
#define SEQ 1024
#define BATCH 4096
#define ROWS 16
#define THREADS 256
#define NTB (SEQ / 64)

typedef __attribute__((ext_vector_type(8))) _Float16 half8;
typedef __attribute__((ext_vector_type(4))) float f32x4;

#define LOG2E 1.44269504088896340736f

__device__ __forceinline__ float rcp_fast(float x) { return __builtin_amdgcn_rcpf(x); }
__device__ __forceinline__ float exp2_fast(float x) { return __builtin_amdgcn_exp2f(x); }
__device__ __forceinline__ f32x4 splat4(float v) { return (f32x4){v, v, v, v}; }

__global__ __launch_bounds__(THREADS, 1) void gru_mfma(
    const float* __restrict__ x,     // [B, T]
    const float* __restrict__ w_ih,  // [192, 1]
    const float* __restrict__ w_hh,  // [192, 64]
    const float* __restrict__ b_ih,  // [192]
    const float* __restrict__ b_hh,  // [192]
    const float* __restrict__ w1,    // [32, 64]
    const float* __restrict__ b1,    // [32]
    const float* __restrict__ w2,    // [16, 32]
    const float* __restrict__ b2,    // [16]
    const float* __restrict__ w3,    // [1, 16]
    const float* __restrict__ b3,    // [1]
    float* __restrict__ out)         // [B, 1]
{
  const int L  = threadIdx.x;        // 0..255
  const int l  = L & 63;             // lane in wave
  const int wv = L >> 6;             // wave 0..3
  const int r0 = blockIdx.x * ROWS;  // first batch row

  // ---------------- LDS ----------------
  // hfrag: fp16 A-fragments, dbuf. Row = 24 halves (48 B) — same byte stride
  // as R5-R7's proven-clean layout; halves 0..7 used per (kt, fraglane).
  __shared__ __align__(16) _Float16 hfrag[2][2][64][24];  // 12 KB
  __shared__ float xbuf[2][ROWS][68];
  __shared__ float ybuf1[ROWS][36];
  __shared__ float ybuf2[ROWS][20];

  // ---------------- W fragments (fp16, prescaled, registers) ----------------
  // Wave wv owns tiles (gate, ub=wv): B[col=16wv+(l&15)][k=kt*32+(l>>4)*8+j].
  // Prescale: r,z by -log2e (sigmoid via rcp(1+exp2(.))); n by +2log2e (tanh).
  half8 bf[3][2];
  {
    const int n0 = l & 15, q = l >> 4;
    const float gscale[3] = {-LOG2E, -LOG2E, 2.0f * LOG2E};
    #pragma unroll
    for (int gate = 0; gate < 3; ++gate) {
      const int c = gate * 64 + 16 * wv + n0;
      #pragma unroll
      for (int kt = 0; kt < 2; ++kt) {
        const float* p = w_hh + c * HID + kt * 32 + q * 8;
        half8 v;
        #pragma unroll
        for (int j = 0; j < 8; ++j) v[j] = (_Float16)(p[j] * gscale[gate]);
        bf[gate][kt] = v;
      }
    }
  }

  // ---------------- per-lane elementwise constants (prescaled) ----------------
  // Lane owns unit u = 16wv + (l&15), rows 4qq..4qq+3 (qq = l>>4).
  const int u  = 16 * wv + (l & 15);
  const int qq = l >> 4;
  const float wir = -LOG2E * w_ih[u];
  const float wiz = -LOG2E * w_ih[64 + u];
  const float win = 2.0f * LOG2E * w_ih[128 + u];
  const float br  = -LOG2E * (b_ih[u] + b_hh[u]);
  const float bz  = -LOG2E * (b_ih[64 + u] + b_hh[64 + u]);
  const float bni = 2.0f * LOG2E * b_ih[128 + u];
  const float bnh = 2.0f * LOG2E * b_hh[128 + u];
  float h[4] = {0.f, 0.f, 0.f, 0.f};

  // h(row m, unit u) -> hfrag[buf][u>>5][m + 16*((u>>3)&3)][u&7]
  const int wkt = u >> 5;
  const int wQ  = (u >> 3) & 3;
  const int wj  = u & 7;

  // zero hfrag (h0 = 0)
  for (int i = L; i < 2 * 2 * 64 * 24 / 2; i += THREADS) ((unsigned*)hfrag)[i] = 0u;

  const float* xblk = x + (size_t)r0 * SEQ;
  const int srow = L >> 4, stq = L & 15;  // staging: 16 rows x 16 quads

  // stage tb=0 into xbuf[0] (visible after step-0 barrier)
  {
    f32x4 v = *(const f32x4*)(xblk + (size_t)srow * SEQ + stq * 4);
    *(f32x4*)&xbuf[0][srow][stq * 4] = v;
  }

  // ---------------- scan ----------------
  for (int tb = 0; tb < NTB; ++tb) {
    const int par = tb & 1;
    const int tbn = (tb < NTB - 1) ? tb + 1 : tb;
    // prefetch next tb's x chunk (64 steps of latency budget)
    f32x4 xg = *(const f32x4*)(xblk + (size_t)srow * SEQ + tbn * 64 + stq * 4);

    #pragma unroll 2
    for (int s = 0; s < 64; ++s) {
      const int cur = s & 1, nxt = cur ^ 1;
      __syncthreads();  // prev step's hfrag writes (and this tb's xbuf) visible

      // ---- A-fragments: single fp16 plane, 2x ds_read_b128 ----
      half8 a0 = *(const half8*)&hfrag[cur][0][l][0];
      half8 a1 = *(const half8*)&hfrag[cur][1][l][0];

      // ---- x for this step (consumed ~200 cyc later; latency covered) ----
      const f32x4 x4 = {xbuf[par][4 * qq + 0][s], xbuf[par][4 * qq + 1][s],
                        xbuf[par][4 * qq + 2][s], xbuf[par][4 * qq + 3][s]};

      // ---- MFMA: 3 gates x (kt0 -> kt1 chained), 6 total ----
      f32x4 acc0 = {0.f, 0.f, 0.f, 0.f};
      f32x4 acc1 = {0.f, 0.f, 0.f, 0.f};
      f32x4 acc2 = {0.f, 0.f, 0.f, 0.f};
      acc0 = __builtin_amdgcn_mfma_f32_16x16x32_f16(a0, bf[0][0], acc0, 0, 0, 0);
      acc1 = __builtin_amdgcn_mfma_f32_16x16x32_f16(a0, bf[1][0], acc1, 0, 0, 0);
      acc2 = __builtin_amdgcn_mfma_f32_16x16x32_f16(a0, bf[2][0], acc2, 0, 0, 0);
      acc0 = __builtin_amdgcn_mfma_f32_16x16x32_f16(a1, bf[0][1], acc0, 0, 0, 0);
      acc1 = __builtin_amdgcn_mfma_f32_16x16x32_f16(a1, bf[1][1], acc1, 0, 0, 0);
      acc2 = __builtin_amdgcn_mfma_f32_16x16x32_f16(a1, bf[2][1], acc2, 0, 0, 0);

      // ---- gate preamble, vectorized (v_pk_fma/add) ----
      f32x4 rpp4 = acc0 + x4 * splat4(wir) + splat4(br);   // -log2e * rpre
      f32x4 zpp4 = acc1 + x4 * splat4(wiz) + splat4(bz);   // -log2e * zpre
      f32x4 np4  = x4 * splat4(win) + splat4(bni);         // 2log2e*(x win + bni)
      f32x4 gn4  = acc2 + splat4(bnh);                     // 2log2e*(ghn + bnh)

      // ---- per-element transcendentals + h update + fp16 store ----
      #pragma unroll
      for (int r = 0; r < 4; ++r) {
        float rr  = rcp_fast(1.0f + exp2_fast(rpp4[r]));
        float zz  = rcp_fast(1.0f + exp2_fast(zpp4[r]));
        float npp = __fmaf_rn(rr, gn4[r], np4[r]);         // 2log2e * npre
        float nn  = __fmaf_rn(-2.0f, rcp_fast(exp2_fast(npp) + 1.0f), 1.0f);
        h[r] = __fmaf_rn(zz, h[r] - nn, nn);
        hfrag[nxt][wkt][16 * wQ + 4 * qq + r][wj] = (_Float16)h[r];
      }
    }

    // stage next tb's x (consumers >= 1 barrier away; WAR-safe as in R7)
    *(f32x4*)&xbuf[par ^ 1][srow][stq * 4] = xg;
  }

  // ---------------- MLP head: 64 -> 32 -> 16 -> 1 ----------------
  __syncthreads();
  #pragma unroll
  for (int r = 0; r < 4; ++r) xbuf[0][4 * qq + r][u] = h[r];  // h fp32 -> LDS
  __syncthreads();

  #pragma unroll
  for (int rep = 0; rep < 2; ++rep) {           // 16 rows x 32 outs = 512 tasks
    const int o = (L & 15) + 16 * rep;
    const int row = L >> 4;
    float a = b1[o];
    #pragma unroll
    for (int j4 = 0; j4 < 16; ++j4) {
      f32x4 wv4 = *(const f32x4*)&w1[o * 64 + 4 * j4];
      f32x4 hv  = *(const f32x4*)&xbuf[0][row][4 * j4];
      a += wv4[0] * hv[0] + wv4[1] * hv[1] + wv4[2] * hv[2] + wv4[3] * hv[3];
    }
    ybuf1[row][o] = (a > 0.0f) ? a : 0.01f * a;
  }
  __syncthreads();

  {
    const int o = L & 15;
    const int row = L >> 4;
    float a = b2[o];
    #pragma unroll
    for (int j4 = 0; j4 < 8; ++j4) {
      f32x4 wv4 = *(const f32x4*)&w2[o * 32 + 4 * j4];
      f32x4 yv  = *(const f32x4*)&ybuf1[row][4 * j4];
      a += wv4[0] * yv[0] + wv4[1] * yv[1] + wv4[2] * yv[2] + wv4[3] * yv[3];
    }
    ybuf2[row][o] = (a > 0.0f) ? a : 0.01f * a;
  }
  __syncthreads();

  if (L < ROWS) {
    float a = b3[0];
    #pragma unroll
    for (int j = 0; j < 16; ++j) a = __fmaf_rn(w3[j], ybuf2[L][j], a);
    out[r0 + L] = a;
  }
}

extern "C" void kernel_launch(void* const* d_in, const int* in_sizes, int n_in,
                              void* d_out, int out_size, void* d_ws, size_t ws_size,
                              hipStream_t stream) {
  const float* x    = (const float*)d_in[0];
  const float* w_ih = (const float*)d_in[1];
  const float* w_hh = (const float*)d_in[2];
  const float* b_ih = (const float*)d_in[3];
  const float* b_hh = (const float*)d_in[4];
  const float* w1   = (const float*)d_in[5];
  const float* b1   = (const float*)d_in[6];
  const float* w2   = (const float*)d_in[7];
  const float* b2   = (const float*)d_in[8];
  const float* w3   = (const float*)d_in[9];
  const float* b3   = (const float*)d_in[10];
  float* out = (float*)d_out;

  dim3 grid(BATCH / ROWS);  // 256 blocks x 4 waves x 16 rows — work-conserving
  dim3 block(THREADS);
  hipLaunchKernelGGL(gru_mfma, grid, block, 0, stream,
                     x, w_ih, w_hh, b_ih, b_hh, w1, b1, w2, b2, w3, b3, out);
}